// Round 12
// baseline (34.698 us; speedup 1.0000x reference)
//
#include <hip/hip_runtime.h>
#include <hip/hip_bf16.h>

// FSMN: strided dilated depthwise conv over time + residual.
// R7-R11 lesson: the compiler never keeps a 30+-element input window live in
// VGPRs (sinks/re-reads), so window-centric designs stall.
// R12: invert the dataflow — keep 8 ACCUMULATORS live (compiler must), stream
// the 37 input rows once each, FMA each row into the 1-4 outputs it feeds
// (static, fully unrolled). Loads are consumed immediately (nothing to sink);
// ILP = 37 independent loads + 8 acc chains, 4-row chunks, 1-chunk lookahead.
// Through-L1 bytes: 4.6 loads/output (vs 16 in R2). f32x2 columns.

typedef float f32x2 __attribute__((ext_vector_type(2)));

constexpr int B = 16;
constexpr int T = 2000;
constexpr int D2 = 256;           // f32x2 columns per row
constexpr int NTAP = 16;          // filt rows: 0..9 left, 10 center, 11..15 right
constexpr int RT = 8;             // outputs per thread
constexpr int NTG = T / RT;       // 250 t-groups
constexpr int WR = RT + 29;       // 37 rows: [t0-20 .. t0+16]
constexpr int CH = 4;             // chunk rows
constexpr int NG = (WR + CH - 1) / CH;   // 10 chunks
constexpr int NXCD = 8;

__device__ __forceinline__ f32x2 zero2() { f32x2 z; z.x = 0.0f; z.y = 0.0f; return z; }

template<bool GUARD>
__device__ __forceinline__ void run_strip(const f32x2* __restrict__ xp,
                                          const f32x2* __restrict__ F,
                                          f32x2* __restrict__ acc, int t0) {
    f32x2 cur[CH];
#pragma unroll
    for (int u = 0; u < CH; ++u) {           // prologue: chunk 0 = rows 0..3
        const int p = t0 - 20 + u;
        cur[u] = (!GUARD || (p >= 0 && p < T)) ? xp[p * D2] : zero2();
    }

#pragma unroll
    for (int g = 0; g < NG; ++g) {
        f32x2 nxt[CH];
#pragma unroll
        for (int u = 0; u < CH; ++u) nxt[u] = zero2();
        if (g + 1 < NG) {                    // lookahead: load chunk g+1
#pragma unroll
            for (int u = 0; u < CH; ++u) {
                const int r = (g + 1) * CH + u;
                if (r < WR) {
                    const int p = t0 - 20 + r;
                    nxt[u] = (!GUARD || (p >= 0 && p < T)) ? xp[p * D2] : zero2();
                }
            }
        }
        // FMA chunk g into the accumulators it feeds
#pragma unroll
        for (int u = 0; u < CH; ++u) {
            const int r = g * CH + u;
            if (r < WR) {
#pragma unroll
                for (int j = 0; j < RT; ++j) {
                    const int o = r - 20 - j;   // tap offset feeding output j
                    const bool ev = (o >= -20) && (o <= 0) && ((o & 1) == 0);
                    const bool od = (o >= 1) && (o <= 9) && ((o & 1) == 1);
                    if (ev || od) {             // folds at compile time
                        const int k = ev ? (o + 20) / 2 : 11 + (o - 1) / 2;
                        acc[j].x = fmaf(cur[u].x, F[k].x, acc[j].x);
                        acc[j].y = fmaf(cur[u].y, F[k].y, acc[j].y);
                    }
                }
            }
        }
        if (g + 1 < NG) {
#pragma unroll
            for (int u = 0; u < CH; ++u) cur[u] = nxt[u];
        }
    }
}

__global__ __launch_bounds__(256) void fsmn_acc_kernel(
    const f32x2* __restrict__ x,      // (B,T,D2)
    const f32x2* __restrict__ filt,   // (16,D2)
    f32x2* __restrict__ out)          // (B,T,D2)
{
    // grid = B*NTG = 4000; bid -> (b, tgroup), tgroup fastest so neighbor
    // groups (sharing the 29-row halo) land on the same XCD's L2 chunk.
    const int nbl = B * NTG;
    const int cpx = nbl / NXCD;              // 500
    int bid = blockIdx.x;
    bid = (bid & (NXCD - 1)) * cpx + (bid >> 3);   // chunked XCD swizzle

    const int tg = bid % NTG;
    const int b  = bid / NTG;
    const int t0 = tg * RT;
    const int c  = (int)threadIdx.x;         // f2 column 0..255 (full D)

    const f32x2* xp = x + (size_t)(b * T) * D2 + c;

    // filter taps for this d-pair; residual folded into center tap
    f32x2 F[NTAP];
#pragma unroll
    for (int k = 0; k < NTAP; ++k) F[k] = filt[k * D2 + c];
    F[10].x += 1.0f;
    F[10].y += 1.0f;

    f32x2 acc[RT];
#pragma unroll
    for (int j = 0; j < RT; ++j) acc[j] = zero2();

    // interior iff rows [t0-20, t0+16] all within [0,T)
    if (t0 >= 20 && t0 + 17 <= T) run_strip<false>(xp, F, acc, t0);
    else                          run_strip<true >(xp, F, acc, t0);

    f32x2* op = out + (size_t)(b * T + t0) * D2 + c;
#pragma unroll
    for (int j = 0; j < RT; ++j) {
        // nontemporal: output never re-read — keep L2/L3 for the input halo
        __builtin_nontemporal_store(acc[j], &op[j * D2]);
    }
}

extern "C" void kernel_launch(void* const* d_in, const int* in_sizes, int n_in,
                              void* d_out, int out_size, void* d_ws, size_t ws_size,
                              hipStream_t stream) {
    const f32x2* x    = (const f32x2*)d_in[0];
    const f32x2* filt = (const f32x2*)d_in[1];
    f32x2* out        = (f32x2*)d_out;

    const int grid = B * NTG;   // 4000 blocks, /8 XCDs evenly
    fsmn_acc_kernel<<<grid, 256, 0, stream>>>(x, filt, out);
}

// Round 13
// 29.250 us; speedup vs baseline: 1.1862x; 1.1862x over previous
//
#include <hip/hip_runtime.h>
#include <hip/hip_bf16.h>

// FSMN: strided dilated depthwise conv over time + residual.
// R7-R12 lesson: R5's ring (25.5us) beats flat windows, LDS tiles, and
// acc-streaming — the compiler handles its small live set + L1 reloads well.
// Realistic floor: 64MB write + 64MB read (half L3) mixed-stream ~= 21-23us.
// R13: the one unconfounded lever left — f32x2 on the PROVEN ring structure
// (R6/R7 confounded f32x2 with the failed flat window). Halves mem
// instructions per byte, doubles per-thread FMA ILP. Interior strips (1..98)
// templated branch-free; edge strips keep guards.

typedef float f32x2 __attribute__((ext_vector_type(2)));

constexpr int B = 16;
constexpr int T = 2000;
constexpr int D2 = 256;           // f32x2 columns per (b,t) row
constexpr int NTAP = 16;          // filt rows: 0..9 left, 10 center, 11..15 right
constexpr int S = 20;             // outputs per thread strip
constexpr int NSTRIP = T / S;     // 100
constexpr int ITERS = S / 2;      // 10 double-steps
constexpr int NXCD = 8;
constexpr int P = 4;              // prefetch depth in double-steps
constexpr int RING = 32 + 2 * (P - 1);   // 38 live slots: [t-20, t+17]

__device__ __forceinline__ f32x2 zero2() { f32x2 z; z.x = 0.0f; z.y = 0.0f; return z; }

template<bool GUARD>
__device__ __forceinline__ void run_strip(const f32x2* __restrict__ xp,
                                          f32x2* __restrict__ op,
                                          const f32x2* __restrict__ F, int t0) {
    // ring window: W[(p - (t0-20)) % RING] holds x[b, p, d-pair]
    // init covers [t0-20, t0+17]; upper bound t0+17 <= 1997 < T always.
    f32x2 W[RING];
#pragma unroll
    for (int m = 0; m < RING; ++m) {
        const int p = t0 - 20 + m;
        W[m] = (!GUARD || p >= 0) ? xp[p * D2] : zero2();
    }

#pragma unroll
    for (int i = 0; i < ITERS; ++i) {
        const int base = (2 * i) % RING;      // slot of (t-20), t = t0+2i
        // tap k=0 consumed FIRST: slots base, base+1 hold the oldest rows and
        // are immediately reused by the prefetch writes below.
        f32x2 a0 = W[base] * F[0];
        f32x2 a1 = W[(base + 1) % RING] * F[0];

        // prefetch the pair first consumed ~P iterations ahead
        if (i + P < ITERS) {                  // compile-time under full unroll
            const int p0 = t0 + 18 + 2 * i;
            const int p1 = p0 + 1;
            W[base]              = (!GUARD || p0 < T) ? xp[p0 * D2] : zero2();
            W[(base + 1) % RING] = (!GUARD || p1 < T) ? xp[p1 * D2] : zero2();
        }

        // even-offset taps k=1..10 (rel = 2k-20); center k=10 has +1 folded
#pragma unroll
        for (int k = 1; k <= 10; ++k) {
            a0 += W[(base + 2 * k) % RING]     * F[k];
            a1 += W[(base + 1 + 2 * k) % RING] * F[k];
        }
        // odd-offset taps k=11..15 (rel = 2k-21)
#pragma unroll
        for (int k = 11; k <= 15; ++k) {
            a0 += W[(base + 2 * k - 1) % RING] * F[k];
            a1 += W[(base + 2 * k) % RING]     * F[k];
        }

        // nontemporal: output is never re-read — keep L2/L3 for input reuse
        __builtin_nontemporal_store(a0, &op[(2 * i) * D2]);
        __builtin_nontemporal_store(a1, &op[(2 * i + 1) * D2]);
    }
}

__global__ __launch_bounds__(256, 4) void fsmn_ring2_kernel(
    const f32x2* __restrict__ x,      // (B,T,D2)
    const f32x2* __restrict__ filt,   // (16,D2)
    f32x2* __restrict__ out)          // (B,T,D2)
{
    // grid = B*NSTRIP = 1600 blocks; bid -> (b, strip), strip fastest so
    // adjacent strips (sharing halo rows) land on the same XCD chunk.
    const int nbl = B * NSTRIP;              // 1600
    const int cpx = nbl / NXCD;              // 200
    int bid = blockIdx.x;
    bid = (bid & (NXCD - 1)) * cpx + (bid >> 3);   // chunked XCD swizzle

    const int strip = bid % NSTRIP;
    const int b     = bid / NSTRIP;
    const int d2    = (int)threadIdx.x;      // f32x2 column, 0..255 (full D)
    const int t0    = strip * S;

    const f32x2* xp = x + (size_t)(b * T) * D2 + d2;
    f32x2*       op = out + (size_t)(b * T + t0) * D2 + d2;

    // filter taps for this d-pair; residual folded into center tap
    f32x2 F[NTAP];
#pragma unroll
    for (int k = 0; k < NTAP; ++k) F[k] = filt[k * D2 + d2];
    F[10].x += 1.0f;
    F[10].y += 1.0f;

    // interior strips need no bounds checks at all:
    //   init lower bound:  t0-20 >= 0      <=> strip >= 1
    //   prefetch upper:    t0+28 < 2000    <=> strip <= 98
    if (strip >= 1 && strip <= 98) run_strip<false>(xp, op, F, t0);
    else                           run_strip<true >(xp, op, F, t0);
}

extern "C" void kernel_launch(void* const* d_in, const int* in_sizes, int n_in,
                              void* d_out, int out_size, void* d_ws, size_t ws_size,
                              hipStream_t stream) {
    const f32x2* x    = (const f32x2*)d_in[0];
    const f32x2* filt = (const f32x2*)d_in[1];
    f32x2* out        = (f32x2*)d_out;

    const int grid = B * NSTRIP;   // 1600 blocks, /8 XCDs evenly
    fsmn_ring2_kernel<<<grid, 256, 0, stream>>>(x, filt, out);
}